// Round 1
// baseline (335.607 us; speedup 1.0000x reference)
//
#include <hip/hip_runtime.h>
#include <hip/hip_bf16.h>

#define BB 8
#define SS 4096
#define CC 512
#define NTOK (BB*SS)   // 32768

typedef __attribute__((ext_vector_type(8))) short bf16x8;
typedef __attribute__((ext_vector_type(4))) float f32x4;
typedef __attribute__((ext_vector_type(4))) short s16x4;

__device__ __forceinline__ float bf2f(short s) {
  return __uint_as_float(((unsigned)(unsigned short)s) << 16);
}
__device__ __forceinline__ short f2bf(float f) {
  __hip_bfloat16 h = __float2bfloat16(f);
  return *reinterpret_cast<short*>(&h);
}

// ---------------- prep: transpose+cast weights, concat qkv bias ----------------
__global__ __launch_bounds__(256) void prep_weights(
    const float* __restrict__ Wq, const float* __restrict__ Wk, const float* __restrict__ Wv,
    const float* __restrict__ Wo, const float* __restrict__ Wg,
    const float* __restrict__ bq, const float* __restrict__ bk, const float* __restrict__ bv,
    short* __restrict__ WtQKV, short* __restrict__ WtO, short* __restrict__ WtG,
    float* __restrict__ bqkv)
{
  int i = blockIdx.x * 256 + threadIdx.x;
  if (i < 1536 * 512) {                  // WtQKV[n][k] = W*(k, n%512)
    int n = i >> 9, k = i & 511;
    const float* W = (n < 512) ? Wq : (n < 1024) ? Wk : Wv;
    WtQKV[i] = f2bf(W[k * 512 + (n & 511)]);
  }
  if (i < 512 * 512) {                   // WtO[n][k] = Wo[k][n]
    int n = i >> 9, k = i & 511;
    WtO[i] = f2bf(Wo[k * 512 + n]);
  }
  if (i < 128 * 512) {                   // WtG[n][k] = Wg[k][n]
    int n = i >> 9, k = i & 511;
    WtG[i] = f2bf(Wg[k * 128 + n]);
  }
  if (i < 1536) {
    bqkv[i] = (i < 512) ? bq[i] : (i < 1024) ? bk[i - 512] : bv[i - 1024];
  }
}

// ---------------- cast x fp32 -> bf16 ----------------
__global__ __launch_bounds__(256) void cast_x_kernel(const float* __restrict__ x,
                                                     short* __restrict__ xb)
{
  int i = blockIdx.x * 256 + threadIdx.x;   // 4 elems per thread
  float4 v = reinterpret_cast<const float4*>(x)[i];
  s16x4 o;
  o[0] = f2bf(v.x); o[1] = f2bf(v.y); o[2] = f2bf(v.z); o[3] = f2bf(v.w);
  reinterpret_cast<s16x4*>(xb)[i] = o;
}

// ---------------- bf16 MFMA GEMM:  C[M,N] = A[M,K] @ Wt[N,K]^T + bias ----------------
// tile 128x128, 4 waves (2x2), each wave 64x64 = 4x4 frags of 16x16, BK=32.
template<int OUT_BF16>
__global__ __launch_bounds__(256) void gemm_kernel(
    const short* __restrict__ A, int lda,
    const short* __restrict__ Wt,
    const float* __restrict__ bias,
    void* __restrict__ Cp, int ldc, int K)
{
  __shared__ short As[128 * 32];
  __shared__ short Bs[128 * 32];
  const int m0 = blockIdx.y * 128;
  const int n0 = blockIdx.x * 128;
  const int t = threadIdx.x;
  const int lane = t & 63, w = t >> 6;
  const int wm = (w >> 1) * 64, wn = (w & 1) * 64;
  const int lr = lane & 15, kb = (lane >> 4) * 8;

  f32x4 acc[4][4];
#pragma unroll
  for (int i = 0; i < 4; i++)
#pragma unroll
    for (int j = 0; j < 4; j++) acc[i][j] = (f32x4){0.f, 0.f, 0.f, 0.f};

  for (int k0 = 0; k0 < K; k0 += 32) {
    // stage 128x32 of A and of Wt (row-major [row][32])
    {
      int c = t;                       // chunk 0..255
      int row = c >> 2, kc = (c & 3) * 8;
      *(bf16x8*)&As[row * 32 + kc] = *(const bf16x8*)&A[(size_t)(m0 + row) * lda + k0 + kc];
      *(bf16x8*)&Bs[row * 32 + kc] = *(const bf16x8*)&Wt[(size_t)(n0 + row) * K + k0 + kc];
      c = t + 256;                     // chunk 256..511
      row = c >> 2; kc = (c & 3) * 8;
      *(bf16x8*)&As[row * 32 + kc] = *(const bf16x8*)&A[(size_t)(m0 + row) * lda + k0 + kc];
      *(bf16x8*)&Bs[row * 32 + kc] = *(const bf16x8*)&Wt[(size_t)(n0 + row) * K + k0 + kc];
    }
    __syncthreads();
    bf16x8 af[4], bfr[4];
#pragma unroll
    for (int mt = 0; mt < 4; mt++) af[mt]  = *(bf16x8*)&As[(wm + mt * 16 + lr) * 32 + kb];
#pragma unroll
    for (int nt = 0; nt < 4; nt++) bfr[nt] = *(bf16x8*)&Bs[(wn + nt * 16 + lr) * 32 + kb];
#pragma unroll
    for (int mt = 0; mt < 4; mt++)
#pragma unroll
      for (int nt = 0; nt < 4; nt++)
        acc[mt][nt] = __builtin_amdgcn_mfma_f32_16x16x32_bf16(af[mt], bfr[nt], acc[mt][nt], 0, 0, 0);
    __syncthreads();
  }

  // epilogue: D mapping col=lane&15, row=(lane>>4)*4+j
  const int cr = (lane >> 4) * 4;
#pragma unroll
  for (int nt = 0; nt < 4; nt++) {
    int col = n0 + wn + nt * 16 + lr;
    float bv = bias[col];
#pragma unroll
    for (int mt = 0; mt < 4; mt++) {
      int row = m0 + wm + mt * 16 + cr;
#pragma unroll
      for (int j = 0; j < 4; j++) {
        float v = acc[mt][nt][j] + bv;
        if (OUT_BF16) ((short*)Cp)[(size_t)(row + j) * ldc + col] = f2bf(v);
        else          ((float*)Cp)[(size_t)(row + j) * ldc + col] = v;
      }
    }
  }
}

// ---------------- windowed attention (16-token windows) ----------------
// one block per window; qkvb rows [tok][1536] = q|k|v. writes x_local bf16.
__global__ __launch_bounds__(256) void winattn_kernel(const short* __restrict__ qkvb,
                                                      short* __restrict__ xl)
{
  __shared__ float sc[16][16];
  __shared__ float at[16][16];
  __shared__ float vv[16][512];
  const int t0 = blockIdx.x * 16;    // global token base
  const int t = threadIdx.x;

  // stage v (bf16 -> fp32 LDS): 16x512, 8 elems per chunk, 1024 chunks
  for (int c = t; c < 1024; c += 256) {
    int r = c >> 6, kc = (c & 63) * 8;
    bf16x8 pv = *(const bf16x8*)&qkvb[(size_t)(t0 + r) * 1536 + 1024 + kc];
#pragma unroll
    for (int u = 0; u < 8; u++) vv[r][kc + u] = bf2f(pv[u]);
  }

  // scores: thread -> (i = t>>4, j = t&15)
  const int i = t >> 4, j = t & 15;
  const short* qrow = &qkvb[(size_t)(t0 + i) * 1536];
  const short* krow = &qkvb[(size_t)(t0 + j) * 1536 + 512];
  float s = 0.f;
  for (int c = 0; c < 512; c += 8) {
    bf16x8 qa = *(const bf16x8*)&qrow[c];
    bf16x8 ka = *(const bf16x8*)&krow[c];
#pragma unroll
    for (int u = 0; u < 8; u++) s += bf2f(qa[u]) * bf2f(ka[u]);
  }
  sc[i][j] = s * 0.04419417382415922f;   // 1/sqrt(512)
  __syncthreads();

  if (t < 16) {
    float m = sc[t][0];
    for (int jj = 1; jj < 16; jj++) m = fmaxf(m, sc[t][jj]);
    float sum = 0.f;
    for (int jj = 0; jj < 16; jj++) { float e = __expf(sc[t][jj] - m); at[t][jj] = e; sum += e; }
    float inv = 1.0f / sum;
    for (int jj = 0; jj < 16; jj++) at[t][jj] *= inv;
  }
  __syncthreads();

  // x_local[i][c] = sum_j at[i][j] * v[j][c]
  for (int idx = t; idx < 8192; idx += 256) {
    int ii = idx >> 9, c = idx & 511;
    float acc = 0.f;
#pragma unroll
    for (int jj = 0; jj < 16; jj++) acc += at[ii][jj] * vv[jj][c];
    xl[(size_t)(t0 + ii) * 512 + c] = f2bf(acc);
  }
}

// ---------------- kg[b][g][d] = x[b, gidx[g], :] @ Wg + bg  (fp32 exact) ----------------
__global__ __launch_bounds__(256) void kg_kernel(const float* __restrict__ x,
                                                 const float* __restrict__ Wg,
                                                 const float* __restrict__ bg,
                                                 float* __restrict__ kg)
{
  int o = blockIdx.x * 256 + threadIdx.x;   // 4096 outputs
  int d = o & 127, g = (o >> 7) & 3, b = o >> 9;
  const int gidx[4] = {0, 1365, 2730, 4095};
  const float* xr = &x[((size_t)b * SS + gidx[g]) * CC];
  float s = bg[d];
  for (int c = 0; c < CC; c++) s += xr[c] * Wg[c * 128 + d];
  kg[o] = s;
}

// ---------------- kgo[b][g][c] = kg[b][g][:] @ Wgo  (no bgo; added in combine) ----------------
__global__ __launch_bounds__(256) void kgo_kernel(const float* __restrict__ kg,
                                                  const float* __restrict__ Wgo,
                                                  float* __restrict__ kgo)
{
  __shared__ float kr[128];
  int bg_ = blockIdx.x;                 // 0..31
  int t = threadIdx.x;
  if (t < 128) kr[t] = kg[bg_ * 128 + t];
  __syncthreads();
  for (int c = t; c < 512; c += 256) {
    float s = 0.f;
    for (int d = 0; d < 128; d++) s += kr[d] * Wgo[d * 512 + c];
    kgo[bg_ * 512 + c] = s;
  }
}

// ---------------- channel pool: avg & max over C per token ----------------
__global__ __launch_bounds__(256) void pool_kernel(const float* __restrict__ x,
                                                   float* __restrict__ pavg,
                                                   float* __restrict__ pmax)
{
  int tok = blockIdx.x * 4 + (threadIdx.x >> 6);
  int lane = threadIdx.x & 63;
  const float* xr = &x[(size_t)tok * CC];
  float s = 0.f, m = -1e30f;
  for (int c = lane; c < CC; c += 64) { float v = xr[c]; s += v; m = fmaxf(m, v); }
#pragma unroll
  for (int off = 32; off; off >>= 1) {
    s += __shfl_down(s, off);
    m = fmaxf(m, __shfl_down(m, off));
  }
  if (lane == 0) { pavg[tok] = s * (1.0f / CC); pmax[tok] = m; }
}

// ---------------- combine: gattn softmax + conv gate + y = (x+xl+xg)*gate (bf16) ----------------
__global__ __launch_bounds__(256) void combine_kernel(
    const float* __restrict__ x, const float* __restrict__ qg,
    const float* __restrict__ kg, const float* __restrict__ kgo,
    const float* __restrict__ bgo, const float* __restrict__ pavg,
    const float* __restrict__ pmax, const float* __restrict__ conv_w,
    short* __restrict__ ybuf)
{
  int tok = blockIdx.x * 4 + (threadIdx.x >> 6);
  int lane = threadIdx.x & 63;
  int b = tok >> 12, s = tok & 4095;

  // global attention weights
  const float* qr = &qg[(size_t)tok * 128];
  const float* kb_ = &kg[b * 512];
  float p0 = 0.f, p1 = 0.f, p2 = 0.f, p3 = 0.f;
  for (int d = lane; d < 128; d += 64) {
    float q = qr[d];
    p0 += q * kb_[d];
    p1 += q * kb_[128 + d];
    p2 += q * kb_[256 + d];
    p3 += q * kb_[384 + d];
  }
#pragma unroll
  for (int off = 32; off; off >>= 1) {
    p0 += __shfl_xor(p0, off); p1 += __shfl_xor(p1, off);
    p2 += __shfl_xor(p2, off); p3 += __shfl_xor(p3, off);
  }
  const float gs = 0.08838834764831845f;  // 1/sqrt(128)
  p0 *= gs; p1 *= gs; p2 *= gs; p3 *= gs;
  float mx = fmaxf(fmaxf(p0, p1), fmaxf(p2, p3));
  float e0 = __expf(p0 - mx), e1 = __expf(p1 - mx), e2 = __expf(p2 - mx), e3 = __expf(p3 - mx);
  float inv = 1.0f / (e0 + e1 + e2 + e3);
  e0 *= inv; e1 *= inv; e2 *= inv; e3 *= inv;

  // conv gate (zero-padded width-7, channels {avg,max})
  float g = 0.f;
#pragma unroll
  for (int tk = 0; tk < 7; tk++) {
    int ss = s + tk - 3;
    if (ss >= 0 && ss < SS) {
      g += conv_w[tk] * pavg[b * SS + ss] + conv_w[7 + tk] * pmax[b * SS + ss];
    }
  }
  g = 1.0f / (1.0f + __expf(-g));

  const float* xr = &x[(size_t)tok * CC];
  const float* k0r = &kgo[b * 2048];
  short* yr = &ybuf[(size_t)tok * CC];
  for (int c = lane; c < CC; c += 64) {
    float xl = bf2f(yr[c]);
    float xg = e0 * k0r[c] + e1 * k0r[512 + c] + e2 * k0r[1024 + c] + e3 * k0r[1536 + c] + bgo[c];
    yr[c] = f2bf((xr[c] + xl + xg) * g);
  }
}

// ---------------- launcher ----------------
extern "C" void kernel_launch(void* const* d_in, const int* in_sizes, int n_in,
                              void* d_out, int out_size, void* d_ws, size_t ws_size,
                              hipStream_t stream)
{
  const float* x     = (const float*)d_in[0];
  const float* Wq    = (const float*)d_in[1];
  const float* bq    = (const float*)d_in[2];
  const float* Wk    = (const float*)d_in[3];
  const float* bk    = (const float*)d_in[4];
  const float* Wv    = (const float*)d_in[5];
  const float* bv    = (const float*)d_in[6];
  const float* Wo    = (const float*)d_in[7];
  const float* bo    = (const float*)d_in[8];
  const float* Wg    = (const float*)d_in[9];
  const float* bg    = (const float*)d_in[10];
  const float* Wgo   = (const float*)d_in[11];
  const float* bgo   = (const float*)d_in[12];
  const float* convw = (const float*)d_in[13];
  float* out = (float*)d_out;

  char* ws = (char*)d_ws;
  size_t off = 0;
  auto alloc = [&](size_t bytes) -> void* {
    void* p = ws + off;
    off += (bytes + 255) & ~(size_t)255;
    return p;
  };
  short* xb    = (short*)alloc((size_t)NTOK * CC * 2);          // 33.5 MB
  short* qkvb  = (short*)alloc((size_t)NTOK * 3 * CC * 2);      // 100.7 MB
  short* WtQKV = (short*)alloc((size_t)1536 * 512 * 2);
  short* WtO   = (short*)alloc((size_t)512 * 512 * 2);
  short* WtG   = (short*)alloc((size_t)128 * 512 * 2);
  float* bqkv  = (float*)alloc(1536 * 4);
  float* qgb   = (float*)alloc((size_t)NTOK * 128 * 4);         // 16.8 MB
  float* kg    = (float*)alloc(8 * 4 * 128 * 4);
  float* kgo   = (float*)alloc(8 * 4 * 512 * 4);
  float* pavg  = (float*)alloc((size_t)NTOK * 4);
  float* pmax  = (float*)alloc((size_t)NTOK * 4);
  short* ybuf  = (short*)alloc((size_t)NTOK * CC * 2);          // 33.5 MB (xl then y)

  prep_weights<<<3072, 256, 0, stream>>>(Wq, Wk, Wv, Wo, Wg, bq, bk, bv,
                                         WtQKV, WtO, WtG, bqkv);
  cast_x_kernel<<<NTOK * CC / 4 / 256, 256, 0, stream>>>(x, xb);

  // qkv = x @ [Wq|Wk|Wv] + [bq|bk|bv]  (M=32768, N=1536, K=512), bf16 out
  gemm_kernel<1><<<dim3(12, 256), 256, 0, stream>>>(xb, CC, WtQKV, bqkv, qkvb, 1536, CC);

  winattn_kernel<<<NTOK / 16, 256, 0, stream>>>(qkvb, ybuf);

  kg_kernel<<<16, 256, 0, stream>>>(x, Wg, bg, kg);
  kgo_kernel<<<32, 256, 0, stream>>>(kg, Wgo, kgo);
  pool_kernel<<<NTOK / 4, 256, 0, stream>>>(x, pavg, pmax);

  // qg = q @ Wg + bg  (M=32768, N=128, K=512), fp32 out
  gemm_kernel<0><<<dim3(1, 256), 256, 0, stream>>>(qkvb, 1536, WtG, bg, qgb, 128, CC);

  combine_kernel<<<NTOK / 4, 256, 0, stream>>>(x, qgb, kg, kgo, bgo, pavg, pmax, convw, ybuf);

  // out = y @ Wo + bo  (M=32768, N=512, K=512), fp32 out
  gemm_kernel<0><<<dim3(4, 256), 256, 0, stream>>>(ybuf, CC, WtO, bo, out, CC, CC);
}

// Round 2
// 274.173 us; speedup vs baseline: 1.2241x; 1.2241x over previous
//
#include <hip/hip_runtime.h>
#include <hip/hip_bf16.h>

#define BB 8
#define SS 4096
#define CC 512
#define NTOK (BB*SS)   // 32768

typedef __attribute__((ext_vector_type(8))) short bf16x8;
typedef __attribute__((ext_vector_type(4))) float f32x4;
typedef __attribute__((ext_vector_type(4))) short s16x4;

__device__ __forceinline__ float bf2f(short s) {
  return __uint_as_float(((unsigned)(unsigned short)s) << 16);
}
__device__ __forceinline__ short f2bf(float f) {
  __hip_bfloat16 h = __float2bfloat16(f);
  return *reinterpret_cast<short*>(&h);
}

__device__ __forceinline__ f32x4 pv_mfma(s16x4 a, s16x4 b, f32x4 c) {
#if __has_builtin(__builtin_amdgcn_mfma_f32_16x16x16bf16_1k)
  return __builtin_amdgcn_mfma_f32_16x16x16bf16_1k(a, b, c, 0, 0, 0);
#else
  f32x4 d;
  asm volatile("v_mfma_f32_16x16x16_bf16 %0, %1, %2, %3\n\ts_nop 7\n\ts_nop 7"
               : "=v"(d) : "v"(a), "v"(b), "v"(c));
  return d;
#endif
}

// ---------------- prep: transpose+cast weights, concat qkv bias ----------------
__global__ __launch_bounds__(256) void prep_weights(
    const float* __restrict__ Wq, const float* __restrict__ Wk, const float* __restrict__ Wv,
    const float* __restrict__ Wo, const float* __restrict__ Wg,
    const float* __restrict__ bq, const float* __restrict__ bk, const float* __restrict__ bv,
    short* __restrict__ WtQKV, short* __restrict__ WtO, short* __restrict__ WtG,
    float* __restrict__ bqkv)
{
  int i = blockIdx.x * 256 + threadIdx.x;
  if (i < 1536 * 512) {                  // WtQKV[n][k] = W*(k, n%512)
    int n = i >> 9, k = i & 511;
    const float* W = (n < 512) ? Wq : (n < 1024) ? Wk : Wv;
    WtQKV[i] = f2bf(W[k * 512 + (n & 511)]);
  }
  if (i < 512 * 512) {                   // WtO[n][k] = Wo[k][n]
    int n = i >> 9, k = i & 511;
    WtO[i] = f2bf(Wo[k * 512 + n]);
  }
  if (i < 128 * 512) {                   // WtG[n][k] = Wg[k][n]
    int n = i >> 9, k = i & 511;
    WtG[i] = f2bf(Wg[k * 128 + n]);
  }
  if (i < 1536) {
    bqkv[i] = (i < 512) ? bq[i] : (i < 1024) ? bk[i - 512] : bv[i - 1024];
  }
}

// ---------------- cast x fp32 -> bf16 ----------------
__global__ __launch_bounds__(256) void cast_x_kernel(const float* __restrict__ x,
                                                     short* __restrict__ xb)
{
  int i = blockIdx.x * 256 + threadIdx.x;   // 4 elems per thread
  float4 v = reinterpret_cast<const float4*>(x)[i];
  s16x4 o;
  o[0] = f2bf(v.x); o[1] = f2bf(v.y); o[2] = f2bf(v.z); o[3] = f2bf(v.w);
  reinterpret_cast<s16x4*>(xb)[i] = o;
}

// ---------------- bf16 MFMA GEMM:  C[M,N] = A[M,K] @ Wt[N,K]^T + bias ----------------
// tile 128x128, 4 waves (2x2), each wave 64x64 = 4x4 frags of 16x16, BK=32.
template<int OUT_BF16>
__global__ __launch_bounds__(256) void gemm_kernel(
    const short* __restrict__ A, int lda,
    const short* __restrict__ Wt,
    const float* __restrict__ bias,
    void* __restrict__ Cp, int ldc, int K)
{
  __shared__ short As[128 * 32];
  __shared__ short Bs[128 * 32];
  const int m0 = blockIdx.y * 128;
  const int n0 = blockIdx.x * 128;
  const int t = threadIdx.x;
  const int lane = t & 63, w = t >> 6;
  const int wm = (w >> 1) * 64, wn = (w & 1) * 64;
  const int lr = lane & 15, kb = (lane >> 4) * 8;

  f32x4 acc[4][4];
#pragma unroll
  for (int i = 0; i < 4; i++)
#pragma unroll
    for (int j = 0; j < 4; j++) acc[i][j] = (f32x4){0.f, 0.f, 0.f, 0.f};

  for (int k0 = 0; k0 < K; k0 += 32) {
    // stage 128x32 of A and of Wt (row-major [row][32])
    {
      int c = t;                       // chunk 0..255
      int row = c >> 2, kc = (c & 3) * 8;
      *(bf16x8*)&As[row * 32 + kc] = *(const bf16x8*)&A[(size_t)(m0 + row) * lda + k0 + kc];
      *(bf16x8*)&Bs[row * 32 + kc] = *(const bf16x8*)&Wt[(size_t)(n0 + row) * K + k0 + kc];
      c = t + 256;                     // chunk 256..511
      row = c >> 2; kc = (c & 3) * 8;
      *(bf16x8*)&As[row * 32 + kc] = *(const bf16x8*)&A[(size_t)(m0 + row) * lda + k0 + kc];
      *(bf16x8*)&Bs[row * 32 + kc] = *(const bf16x8*)&Wt[(size_t)(n0 + row) * K + k0 + kc];
    }
    __syncthreads();
    bf16x8 af[4], bfr[4];
#pragma unroll
    for (int mt = 0; mt < 4; mt++) af[mt]  = *(bf16x8*)&As[(wm + mt * 16 + lr) * 32 + kb];
#pragma unroll
    for (int nt = 0; nt < 4; nt++) bfr[nt] = *(bf16x8*)&Bs[(wn + nt * 16 + lr) * 32 + kb];
#pragma unroll
    for (int mt = 0; mt < 4; mt++)
#pragma unroll
      for (int nt = 0; nt < 4; nt++)
        acc[mt][nt] = __builtin_amdgcn_mfma_f32_16x16x32_bf16(af[mt], bfr[nt], acc[mt][nt], 0, 0, 0);
    __syncthreads();
  }

  // epilogue: D mapping col=lane&15, row=(lane>>4)*4+j
  const int cr = (lane >> 4) * 4;
#pragma unroll
  for (int nt = 0; nt < 4; nt++) {
    int col = n0 + wn + nt * 16 + lr;
    float bv = bias[col];
#pragma unroll
    for (int mt = 0; mt < 4; mt++) {
      int row = m0 + wm + mt * 16 + cr;
#pragma unroll
      for (int j = 0; j < 4; j++) {
        float v = acc[mt][nt][j] + bv;
        if (OUT_BF16) ((short*)Cp)[(size_t)(row + j) * ldc + col] = f2bf(v);
        else          ((float*)Cp)[(size_t)(row + j) * ldc + col] = v;
      }
    }
  }
}

// ---------------- windowed attention v2: MFMA, no LDS ----------------
// Block = 256 threads = 4 waves; 2 windows per block; wave w: window w>>1, col-half w&1.
// Swapped QK^T (A=K, B=Q) -> lane holds S[q=lane&15][key=(lane>>4)*4+jj], softmax is
// 2x shfl_xor; P lands exactly in the 16x16x16 A-operand layout for PV.
__global__ __launch_bounds__(256) void winattn_kernel(const short* __restrict__ qkvb,
                                                      short* __restrict__ xl)
{
  const int t = threadIdx.x;
  const int lane = t & 63, w = t >> 6;
  const int t0 = (blockIdx.x * 2 + (w >> 1)) * 16;   // window token base
  const int half = w & 1;                            // col half: 0 -> [0,256), 1 -> [256,512)

  const int qrow = lane & 15;          // query index for the S values this lane holds
  const int grp8 = (lane >> 4) * 8;    // k-offset of the bf16x8 fragment
  const int krow = (lane >> 4) * 4;    // key base for S / V-row base / D-row base

  // ---- QK^T (swapped): S^T = K @ Q^T ----
  const short* kqbase = &qkvb[(size_t)(t0 + qrow) * 1536];
  f32x4 acc = (f32x4){0.f, 0.f, 0.f, 0.f};
#pragma unroll
  for (int k0 = 0; k0 < 512; k0 += 32) {
    bf16x8 kf = *(const bf16x8*)&kqbase[512 + k0 + grp8];   // K row (qrow), k-chunk
    bf16x8 qf = *(const bf16x8*)&kqbase[k0 + grp8];         // Q row (qrow) as B-operand
    acc = __builtin_amdgcn_mfma_f32_16x16x32_bf16(kf, qf, acc, 0, 0, 0);
  }

  // ---- softmax over keys (16 per query: 4 in-lane x 4 lane-groups) ----
  const float scale = 0.04419417382415922f;  // 1/sqrt(512)
  float s0 = acc[0] * scale, s1 = acc[1] * scale, s2 = acc[2] * scale, s3 = acc[3] * scale;
  float m = fmaxf(fmaxf(s0, s1), fmaxf(s2, s3));
  m = fmaxf(m, __shfl_xor(m, 16));
  m = fmaxf(m, __shfl_xor(m, 32));
  float e0 = __expf(s0 - m), e1 = __expf(s1 - m), e2 = __expf(s2 - m), e3 = __expf(s3 - m);
  float sum = e0 + e1 + e2 + e3;
  sum += __shfl_xor(sum, 16);
  sum += __shfl_xor(sum, 32);
  float inv = 1.0f / sum;
  s16x4 pa;
  pa[0] = f2bf(e0 * inv); pa[1] = f2bf(e1 * inv);
  pa[2] = f2bf(e2 * inv); pa[3] = f2bf(e3 * inv);
  // lane now holds P[q=qrow][key=krow+jj]  == A-frag of mfma_f32_16x16x16_bf16

  // ---- PV: out[q][c] = sum_j P[q][j] V[j][c], 16 col-tiles of 16 ----
  const short* vbase = &qkvb[(size_t)t0 * 1536 + 1024];
  const int colo = lane & 15;
#pragma unroll
  for (int ct = 0; ct < 16; ct++) {
    const int c0 = half * 256 + ct * 16;
    s16x4 bf;
#pragma unroll
    for (int u = 0; u < 4; u++)
      bf[u] = vbase[(size_t)(krow + u) * 1536 + c0 + colo];   // B[k=krow+u][col=colo]
    f32x4 d = pv_mfma(pa, bf, (f32x4){0.f, 0.f, 0.f, 0.f});
#pragma unroll
    for (int jj = 0; jj < 4; jj++)
      xl[(size_t)(t0 + krow + jj) * 512 + c0 + colo] = f2bf(d[jj]);
  }
}

// ---------------- kg[b][g][d] = x[b, gidx[g], :] @ Wg + bg  (fp32 exact) ----------------
__global__ __launch_bounds__(256) void kg_kernel(const float* __restrict__ x,
                                                 const float* __restrict__ Wg,
                                                 const float* __restrict__ bg,
                                                 float* __restrict__ kg)
{
  int o = blockIdx.x * 256 + threadIdx.x;   // 4096 outputs
  int d = o & 127, g = (o >> 7) & 3, b = o >> 9;
  const int gidx[4] = {0, 1365, 2730, 4095};
  const float* xr = &x[((size_t)b * SS + gidx[g]) * CC];
  float s = bg[d];
  for (int c = 0; c < CC; c++) s += xr[c] * Wg[c * 128 + d];
  kg[o] = s;
}

// ---------------- kgo[b][g][c] = kg[b][g][:] @ Wgo  (no bgo; added in combine) ----------------
__global__ __launch_bounds__(256) void kgo_kernel(const float* __restrict__ kg,
                                                  const float* __restrict__ Wgo,
                                                  float* __restrict__ kgo)
{
  __shared__ float kr[128];
  int bg_ = blockIdx.x;                 // 0..31
  int t = threadIdx.x;
  if (t < 128) kr[t] = kg[bg_ * 128 + t];
  __syncthreads();
  for (int c = t; c < 512; c += 256) {
    float s = 0.f;
    for (int d = 0; d < 128; d++) s += kr[d] * Wgo[d * 512 + c];
    kgo[bg_ * 512 + c] = s;
  }
}

// ---------------- channel pool: avg & max over C per token ----------------
__global__ __launch_bounds__(256) void pool_kernel(const float* __restrict__ x,
                                                   float* __restrict__ pavg,
                                                   float* __restrict__ pmax)
{
  int tok = blockIdx.x * 4 + (threadIdx.x >> 6);
  int lane = threadIdx.x & 63;
  const float* xr = &x[(size_t)tok * CC];
  float s = 0.f, m = -1e30f;
  for (int c = lane; c < CC; c += 64) { float v = xr[c]; s += v; m = fmaxf(m, v); }
#pragma unroll
  for (int off = 32; off; off >>= 1) {
    s += __shfl_down(s, off);
    m = fmaxf(m, __shfl_down(m, off));
  }
  if (lane == 0) { pavg[tok] = s * (1.0f / CC); pmax[tok] = m; }
}

// ---------------- combine: gattn softmax + conv gate + y = (x+xl+xg)*gate (bf16) ----------------
__global__ __launch_bounds__(256) void combine_kernel(
    const float* __restrict__ x, const float* __restrict__ qg,
    const float* __restrict__ kg, const float* __restrict__ kgo,
    const float* __restrict__ bgo, const float* __restrict__ pavg,
    const float* __restrict__ pmax, const float* __restrict__ conv_w,
    short* __restrict__ ybuf)
{
  int tok = blockIdx.x * 4 + (threadIdx.x >> 6);
  int lane = threadIdx.x & 63;
  int b = tok >> 12, s = tok & 4095;

  // global attention weights
  const float* qr = &qg[(size_t)tok * 128];
  const float* kb_ = &kg[b * 512];
  float p0 = 0.f, p1 = 0.f, p2 = 0.f, p3 = 0.f;
  for (int d = lane; d < 128; d += 64) {
    float q = qr[d];
    p0 += q * kb_[d];
    p1 += q * kb_[128 + d];
    p2 += q * kb_[256 + d];
    p3 += q * kb_[384 + d];
  }
#pragma unroll
  for (int off = 32; off; off >>= 1) {
    p0 += __shfl_xor(p0, off); p1 += __shfl_xor(p1, off);
    p2 += __shfl_xor(p2, off); p3 += __shfl_xor(p3, off);
  }
  const float gs = 0.08838834764831845f;  // 1/sqrt(128)
  p0 *= gs; p1 *= gs; p2 *= gs; p3 *= gs;
  float mx = fmaxf(fmaxf(p0, p1), fmaxf(p2, p3));
  float e0 = __expf(p0 - mx), e1 = __expf(p1 - mx), e2 = __expf(p2 - mx), e3 = __expf(p3 - mx);
  float inv = 1.0f / (e0 + e1 + e2 + e3);
  e0 *= inv; e1 *= inv; e2 *= inv; e3 *= inv;

  // conv gate (zero-padded width-7, channels {avg,max})
  float g = 0.f;
#pragma unroll
  for (int tk = 0; tk < 7; tk++) {
    int ss = s + tk - 3;
    if (ss >= 0 && ss < SS) {
      g += conv_w[tk] * pavg[b * SS + ss] + conv_w[7 + tk] * pmax[b * SS + ss];
    }
  }
  g = 1.0f / (1.0f + __expf(-g));

  const float* xr = &x[(size_t)tok * CC];
  const float* k0r = &kgo[b * 2048];
  short* yr = &ybuf[(size_t)tok * CC];
  for (int c = lane; c < CC; c += 64) {
    float xl = bf2f(yr[c]);
    float xg = e0 * k0r[c] + e1 * k0r[512 + c] + e2 * k0r[1024 + c] + e3 * k0r[1536 + c] + bgo[c];
    yr[c] = f2bf((xr[c] + xl + xg) * g);
  }
}

// ---------------- launcher ----------------
extern "C" void kernel_launch(void* const* d_in, const int* in_sizes, int n_in,
                              void* d_out, int out_size, void* d_ws, size_t ws_size,
                              hipStream_t stream)
{
  const float* x     = (const float*)d_in[0];
  const float* Wq    = (const float*)d_in[1];
  const float* bq    = (const float*)d_in[2];
  const float* Wk    = (const float*)d_in[3];
  const float* bk    = (const float*)d_in[4];
  const float* Wv    = (const float*)d_in[5];
  const float* bv    = (const float*)d_in[6];
  const float* Wo    = (const float*)d_in[7];
  const float* bo    = (const float*)d_in[8];
  const float* Wg    = (const float*)d_in[9];
  const float* bg    = (const float*)d_in[10];
  const float* Wgo   = (const float*)d_in[11];
  const float* bgo   = (const float*)d_in[12];
  const float* convw = (const float*)d_in[13];
  float* out = (float*)d_out;

  char* ws = (char*)d_ws;
  size_t off = 0;
  auto alloc = [&](size_t bytes) -> void* {
    void* p = ws + off;
    off += (bytes + 255) & ~(size_t)255;
    return p;
  };
  short* xb    = (short*)alloc((size_t)NTOK * CC * 2);          // 33.5 MB
  short* qkvb  = (short*)alloc((size_t)NTOK * 3 * CC * 2);      // 100.7 MB
  short* WtQKV = (short*)alloc((size_t)1536 * 512 * 2);
  short* WtO   = (short*)alloc((size_t)512 * 512 * 2);
  short* WtG   = (short*)alloc((size_t)128 * 512 * 2);
  float* bqkv  = (float*)alloc(1536 * 4);
  float* qgb   = (float*)alloc((size_t)NTOK * 128 * 4);         // 16.8 MB
  float* kg    = (float*)alloc(8 * 4 * 128 * 4);
  float* kgo   = (float*)alloc(8 * 4 * 512 * 4);
  float* pavg  = (float*)alloc((size_t)NTOK * 4);
  float* pmax  = (float*)alloc((size_t)NTOK * 4);
  short* ybuf  = (short*)alloc((size_t)NTOK * CC * 2);          // 33.5 MB (xl then y)

  prep_weights<<<3072, 256, 0, stream>>>(Wq, Wk, Wv, Wo, Wg, bq, bk, bv,
                                         WtQKV, WtO, WtG, bqkv);
  cast_x_kernel<<<NTOK * CC / 4 / 256, 256, 0, stream>>>(x, xb);

  // qkv = x @ [Wq|Wk|Wv] + [bq|bk|bv]  (M=32768, N=1536, K=512), bf16 out
  gemm_kernel<1><<<dim3(12, 256), 256, 0, stream>>>(xb, CC, WtQKV, bqkv, qkvb, 1536, CC);

  winattn_kernel<<<NTOK / 32, 256, 0, stream>>>(qkvb, ybuf);

  kg_kernel<<<16, 256, 0, stream>>>(x, Wg, bg, kg);
  kgo_kernel<<<32, 256, 0, stream>>>(kg, Wgo, kgo);
  pool_kernel<<<NTOK / 4, 256, 0, stream>>>(x, pavg, pmax);

  // qg = q @ Wg + bg  (M=32768, N=128, K=512), fp32 out
  gemm_kernel<0><<<dim3(1, 256), 256, 0, stream>>>(qkvb, 1536, WtG, bg, qgb, 128, CC);

  combine_kernel<<<NTOK / 4, 256, 0, stream>>>(x, qgb, kg, kgo, bgo, pavg, pmax, convw, ybuf);

  // out = y @ Wo + bo  (M=32768, N=512, K=512), fp32 out
  gemm_kernel<0><<<dim3(4, 256), 256, 0, stream>>>(ybuf, CC, WtO, bo, out, CC, CC);
}

// Round 3
// 257.345 us; speedup vs baseline: 1.3041x; 1.0654x over previous
//
#include <hip/hip_runtime.h>
#include <hip/hip_bf16.h>

#define BB 8
#define SS 4096
#define CC 512
#define NTOK (BB*SS)   // 32768

typedef __attribute__((ext_vector_type(8))) short bf16x8;
typedef __attribute__((ext_vector_type(4))) float f32x4;
typedef __attribute__((ext_vector_type(4))) short s16x4;

__device__ __forceinline__ float bf2f(short s) {
  return __uint_as_float(((unsigned)(unsigned short)s) << 16);
}
__device__ __forceinline__ short f2bf(float f) {
  __hip_bfloat16 h = __float2bfloat16(f);
  return *reinterpret_cast<short*>(&h);
}

__device__ __forceinline__ f32x4 pv_mfma(s16x4 a, s16x4 b, f32x4 c) {
#if __has_builtin(__builtin_amdgcn_mfma_f32_16x16x16bf16_1k)
  return __builtin_amdgcn_mfma_f32_16x16x16bf16_1k(a, b, c, 0, 0, 0);
#else
  f32x4 d;
  asm volatile("v_mfma_f32_16x16x16_bf16 %0, %1, %2, %3\n\ts_nop 7\n\ts_nop 7"
               : "=v"(d) : "v"(a), "v"(b), "v"(c));
  return d;
#endif
}

// async global -> LDS, 16B per lane; LDS dest is wave-uniform base + lane*16
__device__ __forceinline__ void gload_lds16(const short* g, short* l) {
  __builtin_amdgcn_global_load_lds(
      (const __attribute__((address_space(1))) unsigned int*)g,
      (__attribute__((address_space(3))) unsigned int*)l, 16, 0, 0);
}

// ---------------- prep: transpose+cast weights, concat qkv bias ----------------
__global__ __launch_bounds__(256) void prep_weights(
    const float* __restrict__ Wq, const float* __restrict__ Wk, const float* __restrict__ Wv,
    const float* __restrict__ Wo, const float* __restrict__ Wg,
    const float* __restrict__ bq, const float* __restrict__ bk, const float* __restrict__ bv,
    short* __restrict__ WtQKV, short* __restrict__ WtO, short* __restrict__ WtG,
    float* __restrict__ bqkv)
{
  int i = blockIdx.x * 256 + threadIdx.x;
  if (i < 1536 * 512) {                  // WtQKV[n][k] = W*(k, n%512)
    int n = i >> 9, k = i & 511;
    const float* W = (n < 512) ? Wq : (n < 1024) ? Wk : Wv;
    WtQKV[i] = f2bf(W[k * 512 + (n & 511)]);
  }
  if (i < 512 * 512) {                   // WtO[n][k] = Wo[k][n]
    int n = i >> 9, k = i & 511;
    WtO[i] = f2bf(Wo[k * 512 + n]);
  }
  if (i < 128 * 512) {                   // WtG[n][k] = Wg[k][n]
    int n = i >> 9, k = i & 511;
    WtG[i] = f2bf(Wg[k * 128 + n]);
  }
  if (i < 1536) {
    bqkv[i] = (i < 512) ? bq[i] : (i < 1024) ? bk[i - 512] : bv[i - 1024];
  }
}

// ---------------- fused: cast x fp32->bf16 + channel pool (avg,max) ----------------
// one wave per token: lane reads 2x float4 (1KB coalesced per wave-half)
__global__ __launch_bounds__(256) void cast_pool_kernel(const float* __restrict__ x,
                                                        short* __restrict__ xb,
                                                        float* __restrict__ pavg,
                                                        float* __restrict__ pmax)
{
  int tok = blockIdx.x * 4 + (threadIdx.x >> 6);
  int lane = threadIdx.x & 63;
  const float* xr = &x[(size_t)tok * CC];
  float4 a = *(const float4*)&xr[lane * 4];
  float4 b = *(const float4*)&xr[256 + lane * 4];
  s16x4 oa, ob;
  oa[0] = f2bf(a.x); oa[1] = f2bf(a.y); oa[2] = f2bf(a.z); oa[3] = f2bf(a.w);
  ob[0] = f2bf(b.x); ob[1] = f2bf(b.y); ob[2] = f2bf(b.z); ob[3] = f2bf(b.w);
  *(s16x4*)&xb[(size_t)tok * CC + lane * 4] = oa;
  *(s16x4*)&xb[(size_t)tok * CC + 256 + lane * 4] = ob;
  float s = (a.x + a.y) + (a.z + a.w) + (b.x + b.y) + (b.z + b.w);
  float m = fmaxf(fmaxf(fmaxf(a.x, a.y), fmaxf(a.z, a.w)),
                  fmaxf(fmaxf(b.x, b.y), fmaxf(b.z, b.w)));
#pragma unroll
  for (int off = 32; off; off >>= 1) {
    s += __shfl_down(s, off);
    m = fmaxf(m, __shfl_down(m, off));
  }
  if (lane == 0) { pavg[tok] = s * (1.0f / CC); pmax[tok] = m; }
}

// ---------------- bf16 MFMA GEMM (m97 structure):  C[M,N] = A[M,K] @ Wt[N,K]^T + bias ----
// tile 128x128, 4 waves (2x2), each wave 64x64 = 4x4 frags of 16x16, BK=32.
// staging via global_load_lds dwordx4: wave w stages A/B rows [w*16,w*16+16) and [64+w*16,...)
template<int OUT_BF16>
__global__ __launch_bounds__(256) void gemm_kernel(
    const short* __restrict__ A, int lda,
    const short* __restrict__ Wt,
    const float* __restrict__ bias,
    void* __restrict__ Cp, int ldc, int K)
{
  __shared__ short As[128 * 32];
  __shared__ short Bs[128 * 32];
  const int m0 = blockIdx.y * 128;
  const int n0 = blockIdx.x * 128;
  const int t = threadIdx.x;
  const int lane = t & 63, w = t >> 6;
  const int wm = (w >> 1) * 64, wn = (w & 1) * 64;
  const int lr = lane & 15, kb = (lane >> 4) * 8;

  // staging addresses: lane covers row (w*16 + lane/4), elems (lane%4)*8
  const int srow = w * 16 + (lane >> 2);
  const int scol = (lane & 3) * 8;
  const short* Ag0 = A + (size_t)(m0 + srow) * lda + scol;
  const short* Ag1 = Ag0 + (size_t)64 * lda;
  const short* Bg0 = Wt + (size_t)(n0 + srow) * K + scol;
  const short* Bg1 = Bg0 + (size_t)64 * K;
  short* Al0 = &As[(w * 16) * 32];
  short* Al1 = &As[(64 + w * 16) * 32];
  short* Bl0 = &Bs[(w * 16) * 32];
  short* Bl1 = &Bs[(64 + w * 16) * 32];

  f32x4 acc[4][4];
#pragma unroll
  for (int i = 0; i < 4; i++)
#pragma unroll
    for (int j = 0; j < 4; j++) acc[i][j] = (f32x4){0.f, 0.f, 0.f, 0.f};

  for (int k0 = 0; k0 < K; k0 += 32) {
    gload_lds16(Ag0 + k0, Al0);
    gload_lds16(Ag1 + k0, Al1);
    gload_lds16(Bg0 + k0, Bl0);
    gload_lds16(Bg1 + k0, Bl1);
    __syncthreads();   // compiler emits vmcnt(0) drain before barrier
    bf16x8 af[4], bfr[4];
#pragma unroll
    for (int mt = 0; mt < 4; mt++) af[mt]  = *(bf16x8*)&As[(wm + mt * 16 + lr) * 32 + kb];
#pragma unroll
    for (int nt = 0; nt < 4; nt++) bfr[nt] = *(bf16x8*)&Bs[(wn + nt * 16 + lr) * 32 + kb];
#pragma unroll
    for (int mt = 0; mt < 4; mt++)
#pragma unroll
      for (int nt = 0; nt < 4; nt++)
        acc[mt][nt] = __builtin_amdgcn_mfma_f32_16x16x32_bf16(af[mt], bfr[nt], acc[mt][nt], 0, 0, 0);
    __syncthreads();
  }

  // epilogue: D mapping col=lane&15, row=(lane>>4)*4+j
  const int cr = (lane >> 4) * 4;
#pragma unroll
  for (int nt = 0; nt < 4; nt++) {
    int col = n0 + wn + nt * 16 + lr;
    float bv = bias[col];
#pragma unroll
    for (int mt = 0; mt < 4; mt++) {
      int row = m0 + wm + mt * 16 + cr;
#pragma unroll
      for (int j = 0; j < 4; j++) {
        float v = acc[mt][nt][j] + bv;
        if (OUT_BF16) ((short*)Cp)[(size_t)(row + j) * ldc + col] = f2bf(v);
        else          ((float*)Cp)[(size_t)(row + j) * ldc + col] = v;
      }
    }
  }
}

// ---------------- windowed attention: MFMA, no LDS ----------------
// Block = 256 threads = 4 waves; 2 windows per block; wave w: window w>>1, col-half w&1.
// Swapped QK^T (A=K, B=Q) -> lane holds S[q=lane&15][key=(lane>>4)*4+jj], softmax is
// 2x shfl_xor; P lands exactly in the 16x16x16 A-operand layout for PV.
__global__ __launch_bounds__(256) void winattn_kernel(const short* __restrict__ qkvb,
                                                      short* __restrict__ xl)
{
  const int t = threadIdx.x;
  const int lane = t & 63, w = t >> 6;
  const int t0 = (blockIdx.x * 2 + (w >> 1)) * 16;   // window token base
  const int half = w & 1;                            // col half: 0 -> [0,256), 1 -> [256,512)

  const int qrow = lane & 15;          // query index for the S values this lane holds
  const int grp8 = (lane >> 4) * 8;    // k-offset of the bf16x8 fragment
  const int krow = (lane >> 4) * 4;    // key base for S / V-row base / D-row base

  // ---- QK^T (swapped): S^T = K @ Q^T ----
  const short* kqbase = &qkvb[(size_t)(t0 + qrow) * 1536];
  f32x4 acc = (f32x4){0.f, 0.f, 0.f, 0.f};
#pragma unroll
  for (int k0 = 0; k0 < 512; k0 += 32) {
    bf16x8 kf = *(const bf16x8*)&kqbase[512 + k0 + grp8];   // K row (qrow), k-chunk
    bf16x8 qf = *(const bf16x8*)&kqbase[k0 + grp8];         // Q row (qrow) as B-operand
    acc = __builtin_amdgcn_mfma_f32_16x16x32_bf16(kf, qf, acc, 0, 0, 0);
  }

  // ---- softmax over keys (16 per query: 4 in-lane x 4 lane-groups) ----
  const float scale = 0.04419417382415922f;  // 1/sqrt(512)
  float s0 = acc[0] * scale, s1 = acc[1] * scale, s2 = acc[2] * scale, s3 = acc[3] * scale;
  float m = fmaxf(fmaxf(s0, s1), fmaxf(s2, s3));
  m = fmaxf(m, __shfl_xor(m, 16));
  m = fmaxf(m, __shfl_xor(m, 32));
  float e0 = __expf(s0 - m), e1 = __expf(s1 - m), e2 = __expf(s2 - m), e3 = __expf(s3 - m);
  float sum = e0 + e1 + e2 + e3;
  sum += __shfl_xor(sum, 16);
  sum += __shfl_xor(sum, 32);
  float inv = 1.0f / sum;
  s16x4 pa;
  pa[0] = f2bf(e0 * inv); pa[1] = f2bf(e1 * inv);
  pa[2] = f2bf(e2 * inv); pa[3] = f2bf(e3 * inv);
  // lane now holds P[q=qrow][key=krow+jj]  == A-frag of mfma_f32_16x16x16_bf16

  // ---- PV: out[q][c] = sum_j P[q][j] V[j][c], 16 col-tiles of 16 ----
  const short* vbase = &qkvb[(size_t)t0 * 1536 + 1024];
  const int colo = lane & 15;
#pragma unroll
  for (int ct = 0; ct < 16; ct++) {
    const int c0 = half * 256 + ct * 16;
    s16x4 bf;
#pragma unroll
    for (int u = 0; u < 4; u++)
      bf[u] = vbase[(size_t)(krow + u) * 1536 + c0 + colo];   // B[k=krow+u][col=colo]
    f32x4 d = pv_mfma(pa, bf, (f32x4){0.f, 0.f, 0.f, 0.f});
#pragma unroll
    for (int jj = 0; jj < 4; jj++)
      xl[(size_t)(t0 + krow + jj) * 512 + c0 + colo] = f2bf(d[jj]);
  }
}

// ---------------- kg[b][g][d] = x[b, gidx[g], :] @ Wg + bg  (fp32 exact) ----------------
__global__ __launch_bounds__(256) void kg_kernel(const float* __restrict__ x,
                                                 const float* __restrict__ Wg,
                                                 const float* __restrict__ bg,
                                                 float* __restrict__ kg)
{
  int o = blockIdx.x * 256 + threadIdx.x;   // 4096 outputs
  int d = o & 127, g = (o >> 7) & 3, b = o >> 9;
  const int gidx[4] = {0, 1365, 2730, 4095};
  const float* xr = &x[((size_t)b * SS + gidx[g]) * CC];
  float s = bg[d];
  for (int c = 0; c < CC; c++) s += xr[c] * Wg[c * 128 + d];
  kg[o] = s;
}

// ---------------- kgo[b][g][c] = kg[b][g][:] @ Wgo  (no bgo; added in combine) ----------------
__global__ __launch_bounds__(256) void kgo_kernel(const float* __restrict__ kg,
                                                  const float* __restrict__ Wgo,
                                                  float* __restrict__ kgo)
{
  __shared__ float kr[128];
  int bg_ = blockIdx.x;                 // 0..31
  int t = threadIdx.x;
  if (t < 128) kr[t] = kg[bg_ * 128 + t];
  __syncthreads();
  for (int c = t; c < 512; c += 256) {
    float s = 0.f;
    for (int d = 0; d < 128; d++) s += kr[d] * Wgo[d * 512 + c];
    kgo[bg_ * 512 + c] = s;
  }
}

// ---------------- combine: gattn softmax + conv gate + y = (x+xl+xg)*gate (bf16) ----------------
__global__ __launch_bounds__(256) void combine_kernel(
    const float* __restrict__ x, const float* __restrict__ qg,
    const float* __restrict__ kg, const float* __restrict__ kgo,
    const float* __restrict__ bgo, const float* __restrict__ pavg,
    const float* __restrict__ pmax, const float* __restrict__ conv_w,
    short* __restrict__ ybuf)
{
  int tok = blockIdx.x * 4 + (threadIdx.x >> 6);
  int lane = threadIdx.x & 63;
  int b = tok >> 12, s = tok & 4095;

  // global attention weights
  const float* qr = &qg[(size_t)tok * 128];
  const float* kb_ = &kg[b * 512];
  float p0 = 0.f, p1 = 0.f, p2 = 0.f, p3 = 0.f;
  for (int d = lane; d < 128; d += 64) {
    float q = qr[d];
    p0 += q * kb_[d];
    p1 += q * kb_[128 + d];
    p2 += q * kb_[256 + d];
    p3 += q * kb_[384 + d];
  }
#pragma unroll
  for (int off = 32; off; off >>= 1) {
    p0 += __shfl_xor(p0, off); p1 += __shfl_xor(p1, off);
    p2 += __shfl_xor(p2, off); p3 += __shfl_xor(p3, off);
  }
  const float gs = 0.08838834764831845f;  // 1/sqrt(128)
  p0 *= gs; p1 *= gs; p2 *= gs; p3 *= gs;
  float mx = fmaxf(fmaxf(p0, p1), fmaxf(p2, p3));
  float e0 = __expf(p0 - mx), e1 = __expf(p1 - mx), e2 = __expf(p2 - mx), e3 = __expf(p3 - mx);
  float inv = 1.0f / (e0 + e1 + e2 + e3);
  e0 *= inv; e1 *= inv; e2 *= inv; e3 *= inv;

  // conv gate (zero-padded width-7, channels {avg,max})
  float g = 0.f;
#pragma unroll
  for (int tk = 0; tk < 7; tk++) {
    int ss = s + tk - 3;
    if (ss >= 0 && ss < SS) {
      g += conv_w[tk] * pavg[b * SS + ss] + conv_w[7 + tk] * pmax[b * SS + ss];
    }
  }
  g = 1.0f / (1.0f + __expf(-g));

  const float* xr = &x[(size_t)tok * CC];
  const float* k0r = &kgo[b * 2048];
  short* yr = &ybuf[(size_t)tok * CC];
  for (int c = lane; c < CC; c += 64) {
    float xl = bf2f(yr[c]);
    float xg = e0 * k0r[c] + e1 * k0r[512 + c] + e2 * k0r[1024 + c] + e3 * k0r[1536 + c] + bgo[c];
    yr[c] = f2bf((xr[c] + xl + xg) * g);
  }
}

// ---------------- launcher ----------------
extern "C" void kernel_launch(void* const* d_in, const int* in_sizes, int n_in,
                              void* d_out, int out_size, void* d_ws, size_t ws_size,
                              hipStream_t stream)
{
  const float* x     = (const float*)d_in[0];
  const float* Wq    = (const float*)d_in[1];
  const float* bq    = (const float*)d_in[2];
  const float* Wk    = (const float*)d_in[3];
  const float* bk    = (const float*)d_in[4];
  const float* Wv    = (const float*)d_in[5];
  const float* bv    = (const float*)d_in[6];
  const float* Wo    = (const float*)d_in[7];
  const float* bo    = (const float*)d_in[8];
  const float* Wg    = (const float*)d_in[9];
  const float* bg    = (const float*)d_in[10];
  const float* Wgo   = (const float*)d_in[11];
  const float* bgo   = (const float*)d_in[12];
  const float* convw = (const float*)d_in[13];
  float* out = (float*)d_out;

  char* ws = (char*)d_ws;
  size_t off = 0;
  auto alloc = [&](size_t bytes) -> void* {
    void* p = ws + off;
    off += (bytes + 255) & ~(size_t)255;
    return p;
  };
  short* xb    = (short*)alloc((size_t)NTOK * CC * 2);          // 33.5 MB
  short* qkvb  = (short*)alloc((size_t)NTOK * 3 * CC * 2);      // 100.7 MB
  short* WtQKV = (short*)alloc((size_t)1536 * 512 * 2);
  short* WtO   = (short*)alloc((size_t)512 * 512 * 2);
  short* WtG   = (short*)alloc((size_t)128 * 512 * 2);
  float* bqkv  = (float*)alloc(1536 * 4);
  float* qgb   = (float*)alloc((size_t)NTOK * 128 * 4);         // 16.8 MB
  float* kg    = (float*)alloc(8 * 4 * 128 * 4);
  float* kgo   = (float*)alloc(8 * 4 * 512 * 4);
  float* pavg  = (float*)alloc((size_t)NTOK * 4);
  float* pmax  = (float*)alloc((size_t)NTOK * 4);
  short* ybuf  = (short*)alloc((size_t)NTOK * CC * 2);          // 33.5 MB (xl then y)

  prep_weights<<<3072, 256, 0, stream>>>(Wq, Wk, Wv, Wo, Wg, bq, bk, bv,
                                         WtQKV, WtO, WtG, bqkv);
  cast_pool_kernel<<<NTOK / 4, 256, 0, stream>>>(x, xb, pavg, pmax);

  // qkv = x @ [Wq|Wk|Wv] + [bq|bk|bv]  (M=32768, N=1536, K=512), bf16 out
  gemm_kernel<1><<<dim3(12, 256), 256, 0, stream>>>(xb, CC, WtQKV, bqkv, qkvb, 1536, CC);

  winattn_kernel<<<NTOK / 32, 256, 0, stream>>>(qkvb, ybuf);

  kg_kernel<<<16, 256, 0, stream>>>(x, Wg, bg, kg);
  kgo_kernel<<<32, 256, 0, stream>>>(kg, Wgo, kgo);

  // qg = q @ Wg + bg  (M=32768, N=128, K=512), fp32 out
  gemm_kernel<0><<<dim3(1, 256), 256, 0, stream>>>(qkvb, 1536, WtG, bg, qgb, 128, CC);

  combine_kernel<<<NTOK / 4, 256, 0, stream>>>(x, qgb, kg, kgo, bgo, pavg, pmax, convw, ybuf);

  // out = y @ Wo + bo  (M=32768, N=512, K=512), fp32 out
  gemm_kernel<0><<<dim3(4, 256), 256, 0, stream>>>(ybuf, CC, WtO, bo, out, CC, CC);
}